// Round 8
// baseline (303.533 us; speedup 1.0000x reference)
//
#include <hip/hip_runtime.h>
#include <stdint.h>

// Problem constants
#define B_     16
#define N_     512
#define R_     10
#define DE_    256
#define DR_    64
#define DOUT_  256
#define INDIM_ 3200   // (DE+DR)*R
#define BLK_   320    // DE+DR
#define RN_    5120   // R*N, K-extent of stage B
#define SPLITS_ 8     // stage B split-K factor
#define STEPS_  20    // BK=32 k-steps per split (160 total / 8)

typedef __bf16          v8bf  __attribute__((ext_vector_type(8)));
typedef unsigned short  v8us  __attribute__((ext_vector_type(8)));
typedef unsigned short  v4us  __attribute__((ext_vector_type(4)));
typedef float           f32x4 __attribute__((ext_vector_type(4)));

static __device__ __forceinline__ unsigned short f2b(float f) {
  union { float f; unsigned u; } c; c.f = f;
  unsigned r = c.u + 0x7FFFu + ((c.u >> 16) & 1u);   // RNE
  return (unsigned short)(r >> 16);
}

static __device__ __forceinline__ v8bf us2bf(v8us u) {
  union { v8us u; v8bf b; } c; c.u = u; return c.b;
}

// async global->LDS, 16B per lane; LDS dest = wave-uniform base + lane*16
static __device__ __forceinline__ void gl_lds16(const void* g, void* l) {
  __builtin_amdgcn_global_load_lds(
      (const __attribute__((address_space(1))) void*)g,
      (__attribute__((address_space(3))) void*)l, 16, 0, 0);
}

// ---------------- merged prep: nodeB + WnB + Uf in one launch ------------------
__global__ void prep_all(const float* __restrict__ nf, const float* __restrict__ W,
                         const float* __restrict__ rel,
                         unsigned short* __restrict__ nodeB,
                         unsigned short* __restrict__ WnB,
                         float* __restrict__ Uf) {
  const int bb = blockIdx.x;
  const int tid = threadIdx.x;
  if (bb < 256) {
    const size_t base = (size_t)bb * 8192;
#pragma unroll
    for (int p = 0; p < 4; ++p) {
      size_t off = base + (size_t)p * 2048 + (size_t)tid * 8;
      float4 x = *(const float4*)(nf + off);
      float4 y = *(const float4*)(nf + off + 4);
      v8us u;
      u[0] = f2b(x.x); u[1] = f2b(x.y); u[2] = f2b(x.z); u[3] = f2b(x.w);
      u[4] = f2b(y.x); u[5] = f2b(y.y); u[6] = f2b(y.z); u[7] = f2b(y.w);
      *(v8us*)(nodeB + off) = u;
    }
  } else if (bb < 896) {
    int idx = (bb - 256) * 1024 + tid * 4;          // < 655360, 4-aligned
    int r = idx >> 16;
    int o = (idx >> 8) & 255;
    int d = idx & 255;                               // 4-aligned, stays in row
    float4 x = *(const float4*)(W + (size_t)o * INDIM_ + r * BLK_ + d);
    v4us u;
    u[0] = f2b(x.x); u[1] = f2b(x.y); u[2] = f2b(x.z); u[3] = f2b(x.w);
    *(v4us*)(WnB + idx) = u;
  } else {
    int idx = (bb - 896) * 256 + tid;                // < B*R*DOUT = 40960
    int o  = idx & 255;
    int br = idx >> 8;                                // b*R + r
    int r  = br % R_;
    const float* rp = rel + (size_t)br * DR_;
    const float* wp = W + (size_t)o * INDIM_ + r * BLK_ + DE_;
    float v = 0.f;
#pragma unroll 8
    for (int d = 0; d < DR_; ++d) v += rp[d] * wp[d];
    Uf[idx] = v;
  }
}

// ---------------- stage A v3: r-merged, node-resident (R7-passing) -------------
__global__ void stageA_gemm(const unsigned short* __restrict__ nodeB,
                            const unsigned short* __restrict__ WnB,
                            const float* __restrict__ Uf,
                            unsigned short* __restrict__ Gp) {
  __shared__ unsigned short S[40960];       // 80 KB
  unsigned short* NodeP = S;                // 4 panels x (64m x 64k)  (32 KB)
  unsigned short* Wbuf  = S + 16384;        // 2 bufs  x (128o x 64k)  (32 KB)
  unsigned short* Cb    = S + 32768;        // 128o x 64m              (16 KB)
  const int b  = blockIdx.x;
  const int o0 = blockIdx.y * 128;
  const int m0 = (blockIdx.z & 7) * 64;
  const int r0 = (blockIdx.z >> 3) * 5;
  const int tid  = threadIdx.x;
  const int lane = tid & 63;
  const int wave = tid >> 6;
  const int wm = wave >> 1, wn = wave & 1;
  const int quad = lane >> 4, l16 = lane & 15;
  const int srl = lane >> 3;                // staging row within 8-row group
  const int skc = lane & 7;                 // staging 16B chunk

  const unsigned short* Nb = nodeB + (size_t)b * (N_ * DE_);

  // ---- prologue: resident node panels (panel p = k in [64p, 64p+64))
#pragma unroll
  for (int p = 0; p < 4; ++p)
#pragma unroll
    for (int it = 0; it < 2; ++it) {
      int rowblk = it * 32 + wave * 8;
      int rl = rowblk + srl;
      int kc = skc ^ (rl & 7);
      gl_lds16(Nb + (size_t)(m0 + rl) * DE_ + p * 64 + kc * 8,
               NodeP + p * 4096 + rowblk * 64);
    }
  // ---- prologue: Wn chunk (r0, t=0) -> buf0
  {
    const unsigned short* Wb = WnB + (size_t)r0 * (DOUT_ * DE_);
#pragma unroll
    for (int it = 0; it < 4; ++it) {
      int rowblk = it * 32 + wave * 8;
      int rl = rowblk + srl;
      int kc = skc ^ (rl & 7);
      gl_lds16(Wb + (size_t)(o0 + rl) * DE_ + kc * 8, Wbuf + rowblk * 64);
    }
  }
  __syncthreads();

  for (int rr = 0; rr < 5; ++rr) {
    const int r = r0 + rr;
    f32x4 acc[4][2];
#pragma unroll
    for (int i = 0; i < 4; ++i)
#pragma unroll
      for (int j = 0; j < 2; ++j) acc[i][j] = f32x4{0.f, 0.f, 0.f, 0.f};

#pragma unroll
    for (int t = 0; t < 4; ++t) {
      // prefetch next Wn chunk into buf (t+1)&1
      if (rr < 4 || t < 3) {
        const int nr = (t < 3) ? r : (r + 1);
        const int nt = (t < 3) ? (t + 1) : 0;
        const unsigned short* Wb = WnB + (size_t)nr * (DOUT_ * DE_);
        unsigned short* Wd = Wbuf + ((t + 1) & 1) * 8192;
#pragma unroll
        for (int it = 0; it < 4; ++it) {
          int rowblk = it * 32 + wave * 8;
          int rl = rowblk + srl;
          int kc = skc ^ (rl & 7);
          gl_lds16(Wb + (size_t)(o0 + rl) * DE_ + nt * 64 + kc * 8, Wd + rowblk * 64);
        }
      }
      // compute chunk (r, t): A = Wbuf[t&1] (128o x 64k), B = NodeP[t] (64m x 64k)
      const unsigned short* Wc = Wbuf + (t & 1) * 8192;
      const unsigned short* Np = NodeP + t * 4096;
#pragma unroll
      for (int ks = 0; ks < 2; ++ks) {
        const int kb = ks * 4;
        v8bf av[4], bv[2];
#pragma unroll
        for (int mi = 0; mi < 4; ++mi) {
          int m = wm * 64 + mi * 16 + l16;
          av[mi] = us2bf(*(const v8us*)(Wc + m * 64 + (((kb + quad) ^ (m & 7)) * 8)));
        }
#pragma unroll
        for (int ni = 0; ni < 2; ++ni) {
          int c = wn * 32 + ni * 16 + l16;
          bv[ni] = us2bf(*(const v8us*)(Np + c * 64 + (((kb + quad) ^ (c & 7)) * 8)));
        }
#pragma unroll
        for (int mi = 0; mi < 4; ++mi)
#pragma unroll
          for (int ni = 0; ni < 2; ++ni)
            acc[mi][ni] = __builtin_amdgcn_mfma_f32_16x16x32_bf16(av[mi], bv[ni], acc[mi][ni], 0, 0, 0);
      }
      __syncthreads();   // drains prefetch vmcnt; next buffer ready
    }

    // ---- per-r epilogue: C -> LDS (bf16, +U), then coalesced 16B stores
#pragma unroll
    for (int mi = 0; mi < 4; ++mi)
#pragma unroll
      for (int tt = 0; tt < 4; ++tt) {
        int o_loc = wm * 64 + mi * 16 + quad * 4 + tt;
        float u = Uf[((size_t)b * R_ + r) * DOUT_ + o0 + o_loc];
#pragma unroll
        for (int ni = 0; ni < 2; ++ni) {
          int m_loc = wn * 32 + ni * 16 + l16;
          Cb[o_loc * 64 + m_loc] = f2b(acc[mi][ni][tt] + u);
        }
      }
    __syncthreads();
#pragma unroll
    for (int p = 0; p < 4; ++p) {
      int idx16 = p * 2048 + tid * 8;       // u16 index into Cb
      int orow = idx16 >> 6;                // 0..127
      int moff = idx16 & 63;
      unsigned short* dst = Gp + ((size_t)(b * DOUT_ + o0 + orow)) * RN_ + r * N_ + m0 + moff;
      *(v8us*)dst = *(const v8us*)(Cb + idx16);
    }
    __syncthreads();   // Cb free before next r's writes
  }
}

// ---------------- stage B v7: part[sp][b] = adj(fp32) @ G' slice ---------------
// TLP experiment, de-risked: R6 body ((512,2) not (512,4); fp32 partials).
// 128n x 256o tile, BK=32; per buffer A[128][40] pad (10 KB) + B[256][32]
// XOR-swizzled (16 KB) = 26 KB, double = 52 KB -> 2 blocks/CU. SPLITS=8 ->
// grid 16x4x8 = 512 blocks = 2/CU = 16 waves/CU (4/SIMD): double the TLP of
// every prior stageB. adj read exactly once; Gp reads x4 unchanged. Simple
// single-barrier prefetch loop (counted waits proven neutral in R4);
// co-resident block's compute covers barrier drains (m114 mechanism).
__global__ __launch_bounds__(512, 2)
void stageB_gemm(const float* __restrict__ adj,
                 const unsigned short* __restrict__ Gp,
                 float* __restrict__ part) {
  // per buffer: A 128*40=5120 shorts + B 256*32=8192 shorts = 13312 (26624 B)
  __shared__ unsigned short SB[2 * 13312];  // 52 KB -> 2 blocks/CU
  const int b  = blockIdx.x;
  const int n0 = blockIdx.y * 128;
  const int sp = blockIdx.z;                // k-steps [sp*20, sp*20+20)
  const int tid  = threadIdx.x;
  const int lane = tid & 63;
  const int wave = tid >> 6;
  const int wm = wave >> 2;                 // 0..1 : n 64-row half
  const int wn = wave & 3;                  // 0..3 : o 64-col quarter
  const int quad = lane >> 4, l16 = lane & 15;

  const float* Ab = adj + (size_t)b * (R_ * N_ * N_);
  const unsigned short* Gb = Gp + (size_t)b * (DOUT_ * RN_);

  f32x4 acc[4][4];
#pragma unroll
  for (int i = 0; i < 4; ++i)
#pragma unroll
    for (int j = 0; j < 4; ++j) acc[i][j] = f32x4{0.f, 0.f, 0.f, 0.f};

  // A staging: thread covers row ar (0..127), 8 floats at col ac8*8
  const int ar  = tid >> 2;                 // 0..127
  const int ac8 = tid & 3;                  // which 8-float chunk of 32
  // B staging: per issue s (0,1), wave covers rows s*128 + wave*16 + (lane>>2)
  const int brl = (lane >> 2);              // row within 16-row group
  const int bkc = lane & 3;                 // 16B chunk within 64B row
  const int c0 = sp * STEPS_;               // first 32-wide k-step id

#define ISSUE_B(slot, cc) do { \
    unsigned short* Bd = SB + (slot) * 13312 + 5120; \
    _Pragma("unroll") \
    for (int s = 0; s < 2; ++s) { \
      int gr = s * 128 + wave * 16 + brl; \
      int kc = bkc ^ ((gr >> 1) & 3); \
      gl_lds16(Gb + (size_t)gr * RN_ + (size_t)(cc) * 32 + kc * 8, \
               Bd + (s * 128 + wave * 16) * 32); \
    } } while (0)

#define LOAD_A(cc) do { \
    const float* g = Ab + ((size_t)((cc) >> 4) * N_ + n0 + ar) * N_ \
                     + ((cc) & 15) * 32 + ac8 * 8; \
    a0 = *(const float4*)(g); \
    a1 = *(const float4*)(g + 4); } while (0)

#define CONV_A(slot) do { \
    v8us u; \
    u[0] = f2b(a0.x); u[1] = f2b(a0.y); u[2] = f2b(a0.z); u[3] = f2b(a0.w); \
    u[4] = f2b(a1.x); u[5] = f2b(a1.y); u[6] = f2b(a1.z); u[7] = f2b(a1.w); \
    *(v8us*)(SB + (slot) * 13312 + ar * 40 + ac8 * 8) = u; } while (0)

#define COMPUTE(slot) do { \
    const unsigned short* Alc = SB + (slot) * 13312; \
    const unsigned short* Blc = Alc + 5120; \
    v8bf av[4], bv[4]; \
    _Pragma("unroll") \
    for (int mi = 0; mi < 4; ++mi) { \
      int m = wm * 64 + mi * 16 + l16; \
      av[mi] = us2bf(*(const v8us*)(Alc + m * 40 + quad * 8)); \
    } \
    _Pragma("unroll") \
    for (int ni = 0; ni < 4; ++ni) { \
      int o = wn * 64 + ni * 16 + l16; \
      bv[ni] = us2bf(*(const v8us*)(Blc + o * 32 + ((quad ^ ((o >> 1) & 3)) * 8))); \
    } \
    _Pragma("unroll") \
    for (int mi = 0; mi < 4; ++mi) \
      _Pragma("unroll") \
      for (int ni = 0; ni < 4; ++ni) \
        acc[mi][ni] = __builtin_amdgcn_mfma_f32_16x16x32_bf16(av[mi], bv[ni], acc[mi][ni], 0, 0, 0); \
    } while (0)

  // ---- prologue: stage step c0 into buf0
  {
    float4 a0, a1;
    ISSUE_B(0, c0);
    LOAD_A(c0);
    CONV_A(0);
  }
  __syncthreads();   // drains vmcnt (gl_lds) + lgkm (ds_write)

  for (int t = 0; t < STEPS_; ++t) {
    const int cur = t & 1, nxt = cur ^ 1;
    float4 a0, a1;
    const bool pf = (t + 1 < STEPS_);
    if (pf) {
      ISSUE_B(nxt, c0 + t + 1);
      LOAD_A(c0 + t + 1);
    }
    COMPUTE(cur);
    if (pf) CONV_A(nxt);     // A regs arrived during compute
    __syncthreads();
  }

#undef ISSUE_B
#undef LOAD_A
#undef CONV_A
#undef COMPUTE

  // epilogue: plain coalesced fp32 stores to this split's private partials
  float* pb = part + (((size_t)sp * B_ + b) * N_) * DOUT_;
#pragma unroll
  for (int mi = 0; mi < 4; ++mi)
#pragma unroll
    for (int t4 = 0; t4 < 4; ++t4) {
      int row = n0 + wm * 64 + mi * 16 + quad * 4 + t4;
#pragma unroll
      for (int ni = 0; ni < 4; ++ni) {
        int col = wn * 64 + ni * 16 + l16;
        pb[(size_t)row * DOUT_ + col] = acc[mi][ni][t4];
      }
    }
}

// ---------------- reduce: out = bias + sum_sp part[sp] -------------------------
__global__ void reduce_out(const float* __restrict__ part, const float* __restrict__ bias,
                           float* __restrict__ out) {
  const size_t idx = (size_t)blockIdx.x * 256 + threadIdx.x;  // float4 index
  const size_t stride = (size_t)B_ * N_ * DOUT_ / 4;          // 524288
  f32x4 a = *(const f32x4*)(bias + (idx & 63) * 4);
#pragma unroll
  for (int s = 0; s < SPLITS_; ++s) {
    f32x4 p = *(const f32x4*)((const float*)part + (stride * s + idx) * 4);
    a += p;
  }
  *(f32x4*)(out + idx * 4) = a;
}

// ---------------- launch -------------------------------------------------------
extern "C" void kernel_launch(void* const* d_in, const int* in_sizes, int n_in,
                              void* d_out, int out_size, void* d_ws, size_t ws_size,
                              hipStream_t stream) {
  const float* node = (const float*)d_in[0];
  const float* rel  = (const float*)d_in[1];
  const float* adj  = (const float*)d_in[2];
  const float* W    = (const float*)d_in[3];
  const float* bias = (const float*)d_in[4];
  float* out = (float*)d_out;

  char* ws = (char*)d_ws;
  // layout (112 MB total; pool is 640 MiB per the harness poison fill):
  unsigned short* nodeB = (unsigned short*)(ws);                      // 4 MB
  unsigned short* WnB   = (unsigned short*)(ws + ((size_t)5 << 20));  // 1.25 MB
  float*          Uf    = (float*)         (ws + ((size_t)7 << 20));  // 160 KB
  unsigned short* Gp    = (unsigned short*)(ws + ((size_t)8 << 20));  // 40 MB
  float*          part  = (float*)         (ws + ((size_t)48 << 20)); // 64 MB (8 x 8MB)

  prep_all<<<dim3(1056), 256, 0, stream>>>(node, W, rel, nodeB, WnB, Uf);
  stageA_gemm<<<dim3(B_, 2, 16), 256, 0, stream>>>(nodeB, WnB, Uf, Gp);
  stageB_gemm<<<dim3(B_, N_ / 128, SPLITS_), 512, 0, stream>>>(adj, Gp, part);
  reduce_out<<<dim3((B_ * N_ * DOUT_ / 4) / 256), 256, 0, stream>>>(part, bias, out);
}

// Round 10
// 297.956 us; speedup vs baseline: 1.0187x; 1.0187x over previous
//
#include <hip/hip_runtime.h>
#include <stdint.h>

// Problem constants
#define B_     16
#define N_     512
#define R_     10
#define DE_    256
#define DR_    64
#define DOUT_  256
#define INDIM_ 3200   // (DE+DR)*R
#define BLK_   320    // DE+DR
#define RN_    5120   // R*N, K-extent of stage B
#define SPLITS_ 4     // stage B split-K factor
#define CPS_    20    // BK=64 chunks per split (80 total / 4)

typedef __bf16          v8bf  __attribute__((ext_vector_type(8)));
typedef unsigned short  v8us  __attribute__((ext_vector_type(8)));
typedef unsigned short  v4us  __attribute__((ext_vector_type(4)));
typedef float           f32x4 __attribute__((ext_vector_type(4)));

static __device__ __forceinline__ unsigned short f2b(float f) {
  union { float f; unsigned u; } c; c.f = f;
  unsigned r = c.u + 0x7FFFu + ((c.u >> 16) & 1u);   // RNE
  return (unsigned short)(r >> 16);
}

static __device__ __forceinline__ v8bf us2bf(v8us u) {
  union { v8us u; v8bf b; } c; c.u = u; return c.b;
}

// async global->LDS, 16B per lane; LDS dest = wave-uniform base + lane*16
static __device__ __forceinline__ void gl_lds16(const void* g, void* l) {
  __builtin_amdgcn_global_load_lds(
      (const __attribute__((address_space(1))) void*)g,
      (__attribute__((address_space(3))) void*)l, 16, 0, 0);
}

static __device__ __forceinline__ void waitv4() { asm volatile("s_waitcnt vmcnt(4)" ::: "memory"); }
static __device__ __forceinline__ void waitv0() { asm volatile("s_waitcnt vmcnt(0)" ::: "memory"); }
static __device__ __forceinline__ void waitl0() { asm volatile("s_waitcnt lgkmcnt(0)" ::: "memory"); }
#define SCHED0() __builtin_amdgcn_sched_barrier(0)

// ---------------- merged prep: nodeB + WnB + Uf + bias-fill of out -------------
// blocks [0,256): node fp32->bf16; [256,896): W node-slice -> WnB bf16;
// [896,1056): Uf; [1056,1568): out[b][n][o] = bias[o] (stage B accumulates
// into out via atomicAdd, so the reduce kernel is gone).
__global__ void prep_all(const float* __restrict__ nf, const float* __restrict__ W,
                         const float* __restrict__ rel,
                         unsigned short* __restrict__ nodeB,
                         unsigned short* __restrict__ WnB,
                         float* __restrict__ Uf,
                         const float* __restrict__ bias,
                         float* __restrict__ out) {
  const int bb = blockIdx.x;
  const int tid = threadIdx.x;
  if (bb < 256) {
    const size_t base = (size_t)bb * 8192;
#pragma unroll
    for (int p = 0; p < 4; ++p) {
      size_t off = base + (size_t)p * 2048 + (size_t)tid * 8;
      float4 x = *(const float4*)(nf + off);
      float4 y = *(const float4*)(nf + off + 4);
      v8us u;
      u[0] = f2b(x.x); u[1] = f2b(x.y); u[2] = f2b(x.z); u[3] = f2b(x.w);
      u[4] = f2b(y.x); u[5] = f2b(y.y); u[6] = f2b(y.z); u[7] = f2b(y.w);
      *(v8us*)(nodeB + off) = u;
    }
  } else if (bb < 896) {
    int idx = (bb - 256) * 1024 + tid * 4;          // < 655360, 4-aligned
    int r = idx >> 16;
    int o = (idx >> 8) & 255;
    int d = idx & 255;                               // 4-aligned, stays in row
    float4 x = *(const float4*)(W + (size_t)o * INDIM_ + r * BLK_ + d);
    v4us u;
    u[0] = f2b(x.x); u[1] = f2b(x.y); u[2] = f2b(x.z); u[3] = f2b(x.w);
    *(v4us*)(WnB + idx) = u;
  } else if (bb < 1056) {
    int idx = (bb - 896) * 256 + tid;                // < B*R*DOUT = 40960
    int o  = idx & 255;
    int br = idx >> 8;                                // b*R + r
    int r  = br % R_;
    const float* rp = rel + (size_t)br * DR_;
    const float* wp = W + (size_t)o * INDIM_ + r * BLK_ + DE_;
    float v = 0.f;
#pragma unroll 8
    for (int d = 0; d < DR_; ++d) v += rp[d] * wp[d];
    Uf[idx] = v;
  } else {
    // out = bias broadcast: 512 blocks x 256 thr x 16 floats = 2,097,152
    size_t idx = (size_t)(bb - 1056) * 4096 + (size_t)tid * 16;
    int o = (int)(idx & 255);                        // 16-aligned within o-row
#pragma unroll
    for (int k = 0; k < 4; ++k) {
      float4 bv = *(const float4*)(bias + o + k * 4);
      *(float4*)(out + idx + k * 4) = bv;
    }
  }
}

// ---------------- stage A v3: r-merged, node-resident (R7-passing) -------------
__global__ void stageA_gemm(const unsigned short* __restrict__ nodeB,
                            const unsigned short* __restrict__ WnB,
                            const float* __restrict__ Uf,
                            unsigned short* __restrict__ Gp) {
  __shared__ unsigned short S[40960];       // 80 KB
  unsigned short* NodeP = S;                // 4 panels x (64m x 64k)  (32 KB)
  unsigned short* Wbuf  = S + 16384;        // 2 bufs  x (128o x 64k)  (32 KB)
  unsigned short* Cb    = S + 32768;        // 128o x 64m              (16 KB)
  const int b  = blockIdx.x;
  const int o0 = blockIdx.y * 128;
  const int m0 = (blockIdx.z & 7) * 64;
  const int r0 = (blockIdx.z >> 3) * 5;
  const int tid  = threadIdx.x;
  const int lane = tid & 63;
  const int wave = tid >> 6;
  const int wm = wave >> 1, wn = wave & 1;
  const int quad = lane >> 4, l16 = lane & 15;
  const int srl = lane >> 3;                // staging row within 8-row group
  const int skc = lane & 7;                 // staging 16B chunk

  const unsigned short* Nb = nodeB + (size_t)b * (N_ * DE_);

  // ---- prologue: resident node panels (panel p = k in [64p, 64p+64))
#pragma unroll
  for (int p = 0; p < 4; ++p)
#pragma unroll
    for (int it = 0; it < 2; ++it) {
      int rowblk = it * 32 + wave * 8;
      int rl = rowblk + srl;
      int kc = skc ^ (rl & 7);
      gl_lds16(Nb + (size_t)(m0 + rl) * DE_ + p * 64 + kc * 8,
               NodeP + p * 4096 + rowblk * 64);
    }
  // ---- prologue: Wn chunk (r0, t=0) -> buf0
  {
    const unsigned short* Wb = WnB + (size_t)r0 * (DOUT_ * DE_);
#pragma unroll
    for (int it = 0; it < 4; ++it) {
      int rowblk = it * 32 + wave * 8;
      int rl = rowblk + srl;
      int kc = skc ^ (rl & 7);
      gl_lds16(Wb + (size_t)(o0 + rl) * DE_ + kc * 8, Wbuf + rowblk * 64);
    }
  }
  __syncthreads();

  for (int rr = 0; rr < 5; ++rr) {
    const int r = r0 + rr;
    f32x4 acc[4][2];
#pragma unroll
    for (int i = 0; i < 4; ++i)
#pragma unroll
      for (int j = 0; j < 2; ++j) acc[i][j] = f32x4{0.f, 0.f, 0.f, 0.f};

#pragma unroll
    for (int t = 0; t < 4; ++t) {
      // prefetch next Wn chunk into buf (t+1)&1
      if (rr < 4 || t < 3) {
        const int nr = (t < 3) ? r : (r + 1);
        const int nt = (t < 3) ? (t + 1) : 0;
        const unsigned short* Wb = WnB + (size_t)nr * (DOUT_ * DE_);
        unsigned short* Wd = Wbuf + ((t + 1) & 1) * 8192;
#pragma unroll
        for (int it = 0; it < 4; ++it) {
          int rowblk = it * 32 + wave * 8;
          int rl = rowblk + srl;
          int kc = skc ^ (rl & 7);
          gl_lds16(Wb + (size_t)(o0 + rl) * DE_ + nt * 64 + kc * 8, Wd + rowblk * 64);
        }
      }
      // compute chunk (r, t): A = Wbuf[t&1] (128o x 64k), B = NodeP[t] (64m x 64k)
      const unsigned short* Wc = Wbuf + (t & 1) * 8192;
      const unsigned short* Np = NodeP + t * 4096;
#pragma unroll
      for (int ks = 0; ks < 2; ++ks) {
        const int kb = ks * 4;
        v8bf av[4], bv[2];
#pragma unroll
        for (int mi = 0; mi < 4; ++mi) {
          int m = wm * 64 + mi * 16 + l16;
          av[mi] = us2bf(*(const v8us*)(Wc + m * 64 + (((kb + quad) ^ (m & 7)) * 8)));
        }
#pragma unroll
        for (int ni = 0; ni < 2; ++ni) {
          int c = wn * 32 + ni * 16 + l16;
          bv[ni] = us2bf(*(const v8us*)(Np + c * 64 + (((kb + quad) ^ (c & 7)) * 8)));
        }
#pragma unroll
        for (int mi = 0; mi < 4; ++mi)
#pragma unroll
          for (int ni = 0; ni < 2; ++ni)
            acc[mi][ni] = __builtin_amdgcn_mfma_f32_16x16x32_bf16(av[mi], bv[ni], acc[mi][ni], 0, 0, 0);
      }
      __syncthreads();   // drains prefetch vmcnt; next buffer ready
    }

    // ---- per-r epilogue: C -> LDS (bf16, +U), then coalesced 16B stores
#pragma unroll
    for (int mi = 0; mi < 4; ++mi)
#pragma unroll
      for (int tt = 0; tt < 4; ++tt) {
        int o_loc = wm * 64 + mi * 16 + quad * 4 + tt;
        float u = Uf[((size_t)b * R_ + r) * DOUT_ + o0 + o_loc];
#pragma unroll
        for (int ni = 0; ni < 2; ++ni) {
          int m_loc = wn * 32 + ni * 16 + l16;
          Cb[o_loc * 64 + m_loc] = f2b(acc[mi][ni][tt] + u);
        }
      }
    __syncthreads();
#pragma unroll
    for (int p = 0; p < 4; ++p) {
      int idx16 = p * 2048 + tid * 8;       // u16 index into Cb
      int orow = idx16 >> 6;                // 0..127
      int moff = idx16 & 63;
      unsigned short* dst = Gp + ((size_t)(b * DOUT_ + o0 + orow)) * RN_ + r * N_ + m0 + moff;
      *(v8us*)dst = *(const v8us*)(Cb + idx16);
    }
    __syncthreads();   // Cb free before next r's writes
  }
}

// ---------------- stage B v9: v5 body + fused atomic reduce --------------------
// 128n x 256o tile, BK=64, 8 waves 2x4, 96 KB double buffer, grid 16x4x4 =
// 256 blocks (1/CU). R4/R7-passing counted-wait pipeline unchanged. Epilogue:
// atomicAdd directly into out (pre-filled with bias by prep_all) — kills the
// 32 MB part write + 32 MB part read + 8 MB out write + one kernel launch.
// Exactly 4 splits contend per element, spread in time.
__global__ __launch_bounds__(512, 1)
void stageB_gemm(const float* __restrict__ adj,
                 const unsigned short* __restrict__ Gp,
                 float* __restrict__ out) {
  // per buffer: A 128x64 (8192 u16, 16 KB) + B 256x64 (16384 u16, 32 KB)
  __shared__ unsigned short SB[2 * 24576];  // 96 KB
  const int b  = blockIdx.x;
  const int n0 = blockIdx.y * 128;
  const int sp = blockIdx.z;                // chunks [sp*20, sp*20+20)
  const int tid  = threadIdx.x;
  const int lane = tid & 63;
  const int wave = tid >> 6;
  const int wm = wave >> 2;                 // 0..1 : n 64-row half
  const int wn = wave & 3;                  // 0..3 : o 64-col quarter
  const int quad = lane >> 4, l16 = lane & 15;

  const float* Ab = adj + (size_t)b * (R_ * N_ * N_);
  const unsigned short* Gb = Gp + (size_t)b * (DOUT_ * RN_);

  f32x4 acc[4][4];
#pragma unroll
  for (int i = 0; i < 4; ++i)
#pragma unroll
    for (int j = 0; j < 4; ++j) acc[i][j] = f32x4{0.f, 0.f, 0.f, 0.f};

  // A staging: thread covers rows {ar0, ar0+64}, 8 floats each at col ac8*8
  const int ar0 = tid >> 3;                 // 0..63
  const int ac8 = tid & 7;
  const int acs = ac8 ^ (ar0 & 7);          // XOR slot ((ar0+64)&7 == ar0&7)
  // B staging: per issue-round s, wave covers rows [s*64+wave*8, +8)
  const int brl = wave * 8 + (lane >> 3);
  const int bkc = lane & 7;
  const int c0 = sp * CPS_;                 // first BK=64 chunk id

  float4 As0[4], As1[4];                    // two in-flight A register sets

#define ISSUE_B(slot, cc) do { \
    unsigned short* Bd = SB + (slot) * 24576 + 8192; \
    const int k0b = (cc) << 6; \
    _Pragma("unroll") \
    for (int s = 0; s < 4; ++s) { \
      int rl = s * 64 + brl; \
      int kc = bkc ^ (rl & 7); \
      gl_lds16(Gb + (size_t)rl * RN_ + k0b + kc * 8, Bd + (s * 64 + wave * 8) * 64); \
    } } while (0)

#define ISSUE_A(AR, cc) do { \
    const float* g = Ab + ((size_t)((cc) >> 3) * N_ + n0) * N_ + ((cc) & 7) * 64 \
                     + (size_t)ar0 * N_ + ac8 * 8; \
    AR[0] = *(const float4*)(g); \
    AR[1] = *(const float4*)(g + 4); \
    AR[2] = *(const float4*)(g + 64 * N_); \
    AR[3] = *(const float4*)(g + 64 * N_ + 4); } while (0)

#define CONV_A(AR, slot) do { \
    v8us u0, u1; \
    u0[0] = f2b(AR[0].x); u0[1] = f2b(AR[0].y); u0[2] = f2b(AR[0].z); u0[3] = f2b(AR[0].w); \
    u0[4] = f2b(AR[1].x); u0[5] = f2b(AR[1].y); u0[6] = f2b(AR[1].z); u0[7] = f2b(AR[1].w); \
    u1[0] = f2b(AR[2].x); u1[1] = f2b(AR[2].y); u1[2] = f2b(AR[2].z); u1[3] = f2b(AR[2].w); \
    u1[4] = f2b(AR[3].x); u1[5] = f2b(AR[3].y); u1[6] = f2b(AR[3].z); u1[7] = f2b(AR[3].w); \
    unsigned short* Ad = SB + (slot) * 24576; \
    *(v8us*)(Ad + ar0 * 64 + acs * 8) = u0; \
    *(v8us*)(Ad + (ar0 + 64) * 64 + acs * 8) = u1; } while (0)

#define COMPUTE(slot) do { \
    const unsigned short* Alc = SB + (slot) * 24576; \
    const unsigned short* Blc = Alc + 8192; \
    _Pragma("unroll") \
    for (int ks = 0; ks < 2; ++ks) { \
      const int kb = ks * 4; \
      v8bf av[4], bv[4]; \
      _Pragma("unroll") \
      for (int mi = 0; mi < 4; ++mi) { \
        int m = wm * 64 + mi * 16 + l16; \
        av[mi] = us2bf(*(const v8us*)(Alc + m * 64 + (((kb + quad) ^ (m & 7)) * 8))); \
      } \
      _Pragma("unroll") \
      for (int ni = 0; ni < 4; ++ni) { \
        int o = wn * 64 + ni * 16 + l16; \
        bv[ni] = us2bf(*(const v8us*)(Blc + o * 64 + (((kb + quad) ^ (o & 7)) * 8))); \
      } \
      _Pragma("unroll") \
      for (int mi = 0; mi < 4; ++mi) \
        _Pragma("unroll") \
        for (int ni = 0; ni < 4; ++ni) \
          acc[mi][ni] = __builtin_amdgcn_mfma_f32_16x16x32_bf16(av[mi], bv[ni], acc[mi][ni], 0, 0, 0); \
    } } while (0)

  // ---- prologue. FIFO after issues: [A0(4), B0(4), A1(4)] = 12
  ISSUE_A(As0, c0 + 0);
  ISSUE_B(0, c0 + 0);
  ISSUE_A(As1, c0 + 1);
  waitv4();                 // drains A0 + B0; leaves A1(4) in flight
  SCHED0();
  CONV_A(As0, 0);           // A0 -> LDS slot 0
  waitl0();
  __builtin_amdgcn_s_barrier();

  for (int t = 0; t < CPS_; t += 2) {
    // ---- even sub-iter t
    {
      ISSUE_B(1, c0 + t + 1);
      if (t + 2 < CPS_) ISSUE_A(As0, c0 + t + 2);
      SCHED0();
      COMPUTE(0);
      if (t + 2 < CPS_) waitv4();
      else              waitv0();
      SCHED0();
      CONV_A(As1, 1);
      waitl0();
      __builtin_amdgcn_s_barrier();
    }
    // ---- odd sub-iter t+1
    {
      if (t + 2 < CPS_) {
        ISSUE_B(0, c0 + t + 2);
        if (t + 3 < CPS_) ISSUE_A(As1, c0 + t + 3);
        SCHED0();
        COMPUTE(1);
        if (t + 3 < CPS_) waitv4();
        else              waitv0();
        SCHED0();
        CONV_A(As0, 0);
        waitl0();
        __builtin_amdgcn_s_barrier();
      } else {
        SCHED0();
        COMPUTE(1);
      }
    }
  }

#undef ISSUE_B
#undef ISSUE_A
#undef CONV_A
#undef COMPUTE

  // epilogue: accumulate into out (pre-filled with bias) — fused reduce
  float* ob = out + ((size_t)b * N_) * DOUT_;
#pragma unroll
  for (int mi = 0; mi < 4; ++mi)
#pragma unroll
    for (int t4 = 0; t4 < 4; ++t4) {
      int row = n0 + wm * 64 + mi * 16 + quad * 4 + t4;
#pragma unroll
      for (int ni = 0; ni < 4; ++ni) {
        int col = wn * 64 + ni * 16 + l16;
        atomicAdd(&ob[(size_t)row * DOUT_ + col], acc[mi][ni][t4]);
      }
    }
}

// ---------------- launch -------------------------------------------------------
extern "C" void kernel_launch(void* const* d_in, const int* in_sizes, int n_in,
                              void* d_out, int out_size, void* d_ws, size_t ws_size,
                              hipStream_t stream) {
  const float* node = (const float*)d_in[0];
  const float* rel  = (const float*)d_in[1];
  const float* adj  = (const float*)d_in[2];
  const float* W    = (const float*)d_in[3];
  const float* bias = (const float*)d_in[4];
  float* out = (float*)d_out;

  char* ws = (char*)d_ws;
  // layout (48 MB used):
  unsigned short* nodeB = (unsigned short*)(ws);                      // 4 MB
  unsigned short* WnB   = (unsigned short*)(ws + ((size_t)5 << 20));  // 1.25 MB
  float*          Uf    = (float*)         (ws + ((size_t)7 << 20));  // 160 KB
  unsigned short* Gp    = (unsigned short*)(ws + ((size_t)8 << 20));  // 40 MB

  prep_all<<<dim3(1568), 256, 0, stream>>>(node, W, rel, nodeB, WnB, Uf, bias, out);
  stageA_gemm<<<dim3(B_, 2, 16), 256, 0, stream>>>(nodeB, WnB, Uf, Gp);
  stageB_gemm<<<dim3(B_, N_ / 128, SPLITS_), 512, 0, stream>>>(adj, Gp, out);
}